// Round 10
// baseline (1311.315 us; speedup 1.0000x reference)
//
#include <hip/hip_runtime.h>
#include <hip/hip_bf16.h>

typedef __bf16 bf16;
typedef __attribute__((ext_vector_type(8))) __bf16 bf16x8;
typedef __attribute__((ext_vector_type(4))) float f32x4;

#define T_TOK 8192
#define DIN   4096
#define DOUT  4096
#define RNK   16
#define NS    16
#define KLORA (NS * RNK)   // 256
#define GATE  0.12f

typedef __attribute__((address_space(1))) const void gconst_t;
typedef __attribute__((address_space(3))) void lds_t;

__device__ __forceinline__ void gload_lds16(const void* g, void* l) {
  __builtin_amdgcn_global_load_lds((gconst_t*)g, (lds_t*)l, 16, 0, 0);
}

#define BAR() do { asm volatile("" ::: "memory"); \
                   __builtin_amdgcn_s_barrier();  \
                   asm volatile("" ::: "memory"); } while (0)
#define VMW(n) asm volatile("s_waitcnt vmcnt(" #n ")" ::: "memory")
#define LGKM(n) do { asm volatile("s_waitcnt lgkmcnt(" #n ")" ::: "memory"); \
                     __builtin_amdgcn_sched_barrier(0); } while (0)
#define SB0 __builtin_amdgcn_sched_barrier(0)
#define PRIO1 __builtin_amdgcn_s_setprio(1)
#define PRIO0 __builtin_amdgcn_s_setprio(0)

// ---------------------------------------------------------------- prep kernels

__global__ __launch_bounds__(256)
void cast_x_kernel(const float* __restrict__ x, bf16* __restrict__ xb) {
  const long i = ((long)blockIdx.x * 256 + threadIdx.x) * 8;
  const float4 v0 = *(const float4*)(x + i);
  const float4 v1 = *(const float4*)(x + i + 4);
  bf16x8 o;
  o[0] = (bf16)v0.x; o[1] = (bf16)v0.y; o[2] = (bf16)v0.z; o[3] = (bf16)v0.w;
  o[4] = (bf16)v1.x; o[5] = (bf16)v1.y; o[6] = (bf16)v1.z; o[7] = (bf16)v1.w;
  *(bf16x8*)(xb + i) = o;
}

__global__ __launch_bounds__(256)
void build_bg_kernel(const float* __restrict__ B, const float* __restrict__ dw,
                     const int* __restrict__ sd, bf16* __restrict__ bg) {
  const int t = blockIdx.x * 256 + threadIdx.x;
  const int o = t >> 8, k = t & 255, s = k >> 4, r = k & 15;
  const float w = dw[sd[s]];
  const float g = (w > GATE) ? w : 0.f;
  bg[t] = (bf16)(g * B[((size_t)s * DOUT + o) * RNK + r]);
}

__global__ __launch_bounds__(256)
void transpose_a_kernel(const float* __restrict__ A, bf16* __restrict__ at) {
  __shared__ float t[32][33];
  const int d0 = blockIdx.x * 32, k0 = blockIdx.y * 32;
  const int tx = threadIdx.x & 31, ty = threadIdx.x >> 5;
#pragma unroll
  for (int i = 0; i < 32; i += 8)
    t[ty + i][tx] = A[(size_t)(k0 + ty + i) * DIN + d0 + tx];
  __syncthreads();
#pragma unroll
  for (int i = 0; i < 32; i += 8)
    at[(size_t)(d0 + ty + i) * KLORA + k0 + tx] = (bf16)t[tx][ty + i];
}

// ---------------------------------------------------------------- 128^2 GEMM (W_eff only)
__global__ __launch_bounds__(256)
void gemm_bt(const bf16* __restrict__ Am, const bf16* __restrict__ Bm,
             const float* __restrict__ extra, bf16* __restrict__ outB,
             int M, int N, int K) {
  constexpr int BM = 128, BN = 128, BK = 32;
  __shared__ __align__(16) bf16 At[BM * BK];
  __shared__ __align__(16) bf16 Bt[BN * BK];

  const int tid  = threadIdx.x;
  const int wave = tid >> 6, lane = tid & 63;

  const int nwg = gridDim.x, bid = blockIdx.x;
  const int qq  = nwg >> 3;
  const int sw  = (bid & 7) * qq + (bid >> 3);
  const int ntN = N / BN;
  const long row0 = (long)(sw / ntN) * BM;
  const long col0 = (long)(sw % ntN) * BN;

  f32x4 acc[4][4] = {};
  const int kSteps = K / BK;

  auto stage = [&](int ks) {
    const long k0 = (long)ks * BK;
#pragma unroll
    for (int r = 0; r < 2; ++r) {
      const int off = tid * 16 + r * 4096;
      const int row = off >> 6;
      const int el  = (off & 63) >> 1;
      char* ldsA = (char*)At + (wave << 10) + (r << 12);
      char* ldsB = (char*)Bt + (wave << 10) + (r << 12);
      gload_lds16(Am + (row0 + row) * K + k0 + el, ldsA);
      gload_lds16(Bm + (col0 + row) * K + k0 + el, ldsB);
    }
  };

  stage(0);
  for (int ks = 0; ks < kSteps; ++ks) {
    __syncthreads();
    bf16x8 afr[4], bfr[4];
    const int koff = (lane >> 4) << 3;
    const int rsel = lane & 15;
    const int wr = wave >> 1, wc = wave & 1;
#pragma unroll
    for (int m = 0; m < 4; ++m)
      afr[m] = *(const bf16x8*)&At[((wr << 6) + (m << 4) + rsel) * BK + koff];
#pragma unroll
    for (int n = 0; n < 4; ++n)
      bfr[n] = *(const bf16x8*)&Bt[((wc << 6) + (n << 4) + rsel) * BK + koff];
    __syncthreads();
    if (ks + 1 < kSteps) stage(ks + 1);
#pragma unroll
    for (int m = 0; m < 4; ++m)
#pragma unroll
      for (int n = 0; n < 4; ++n)
        acc[m][n] = __builtin_amdgcn_mfma_f32_16x16x32_bf16(afr[m], bfr[n],
                                                            acc[m][n], 0, 0, 0);
  }

  const int wr = wave >> 1, wc = wave & 1;
#pragma unroll
  for (int m = 0; m < 4; ++m)
#pragma unroll
    for (int n = 0; n < 4; ++n)
#pragma unroll
      for (int j = 0; j < 4; ++j) {
        const long row = row0 + wr * 64 + m * 16 + ((lane >> 4) << 2) + j;
        const long col = col0 + wc * 64 + n * 16 + (lane & 15);
        outB[row * N + col] = (bf16)(acc[m][n][j] + extra[row * N + col]);
      }
}

// ---------------------------------------------------------------- 256^2 GEMM: A via LDS, B streamed global->reg
// out[row][col] = sum_k Am[row][k]*Bm[col][k] + bias[col]   (f32 out)
// BM=BN=256, BK=64 (2 ksubs of 32). 8 waves (2M x 4N), 512 threads.
// LDS: A only — 8 slots x 16KB (256 rows x 32 elems, st_16x32 swizzle);
// half H = 2*tile + ksub, slot = H&7 -> write-vs-last-read distance ~9 barriers.
// Stage cadence: ph1 -> H=2t+4, ph3 -> H=2t+5 (tile t+2's halves).
// B fragments double-buffered in VGPRs (bE/bO) via PLAIN vector loads —
// compiler tracks them (exact counted waits before use; spills safe).
// Per-wave vmcnt FIFO at ph3-end: [A(2t+3), A(2t+4), B(t+1), A(2t+5)];
// uniform VMW(2) retires all but A(2t+5). Prologue: B(0) first, then A 0..3,
// VMW(2) leaves exactly A3 = the loop invariant. Tail (skipped stages) only
// tightens the wait. LGKM(0)+sched_barrier(0) fences phase tops (rule #18).
__global__ __launch_bounds__(512, 2)
void gemm256(const bf16* __restrict__ Am, const bf16* __restrict__ Bm,
             const float* __restrict__ bias, float* __restrict__ out,
             int M, int N, int K) {
  extern __shared__ char smem[];
  const int tid  = threadIdx.x;
  const int wave = tid >> 6, lane = tid & 63;
  const int wr = wave >> 2, wc = wave & 3;       // 2 x 4 wave grid
  const int rsel = lane & 15, klane = lane >> 4;

  const int nwg = gridDim.x, bid = blockIdx.x;   // nwg multiple of 8
  const int sw  = (bid & 7) * (nwg >> 3) + (bid >> 3);
  const int ntN = N >> 8;
  const long row0 = (long)(sw / ntN) << 8;
  const long col0 = (long)(sw % ntN) << 8;

  // A staging: dest (linear) = slot<<14 + (wave*2+r)<<10 + lane*16
  long srcA[2];
  int  ldsd[2];
  {
    const int rlo = lane >> 2;
    const int kbe = (((lane & 3) * 16) ^ (((lane >> 5) & 1) << 5)) >> 1;
#pragma unroll
    for (int r = 0; r < 2; ++r) {
      const int row = wave * 32 + r * 16 + rlo;
      srcA[r] = (row0 + row) * (long)K + kbe;
      ldsd[r] = (wave * 2 + r) << 10;
    }
  }

  const int nT = K >> 6;

  auto stage_half = [&](int H) {                 // H = 2*tile + ksub (A only)
    if (H >= 2 * nT) return;
    const int  slot = H & 7;
    const long kofs = (long)(H >> 1) * 64 + (long)(H & 1) * 32;
#pragma unroll
    for (int r = 0; r < 2; ++r)
      gload_lds16(Am + srcA[r] + kofs, smem + (slot << 14) + ldsd[r]);
  };

  const int laneoff = rsel * 64 + ((klane * 16) ^ ((rsel & 8) << 2));

  f32x4 acc[8][4] = {};
  bf16x8 afr0[4], afr1[4];
  bf16x8 bE[2][4], bO[2][4];                     // [ksub][n] fragments

  const bf16* pB0 = Bm + (col0 + wc * 64 + rsel) * (long)K + klane * 8;

#define LOADB8(tt, BUF) do { \
  const bf16* _p = pB0 + (long)(tt) * 64; \
  BUF[0][0] = *(const bf16x8*)(_p); \
  BUF[0][1] = *(const bf16x8*)(_p + 16L * K); \
  BUF[0][2] = *(const bf16x8*)(_p + 32L * K); \
  BUF[0][3] = *(const bf16x8*)(_p + 48L * K); \
  BUF[1][0] = *(const bf16x8*)(_p + 32); \
  BUF[1][1] = *(const bf16x8*)(_p + 16L * K + 32); \
  BUF[1][2] = *(const bf16x8*)(_p + 32L * K + 32); \
  BUF[1][3] = *(const bf16x8*)(_p + 48L * K + 32); \
} while (0)

#define RDA(slot, mh, mi, dst) \
  (dst)[(mi)] = *(const bf16x8*)(smem + ((slot) << 14) + \
                 (((wr << 7) + (mh) * 64 + (mi) * 16) << 6) + laneoff)

#define MB4(mh, mi, A_, Bv) do { \
  acc[(mh)*4+(mi)][0] = __builtin_amdgcn_mfma_f32_16x16x32_bf16((A_)[(mi)], (Bv)[0], acc[(mh)*4+(mi)][0], 0, 0, 0); \
  acc[(mh)*4+(mi)][1] = __builtin_amdgcn_mfma_f32_16x16x32_bf16((A_)[(mi)], (Bv)[1], acc[(mh)*4+(mi)][1], 0, 0, 0); \
  acc[(mh)*4+(mi)][2] = __builtin_amdgcn_mfma_f32_16x16x32_bf16((A_)[(mi)], (Bv)[2], acc[(mh)*4+(mi)][2], 0, 0, 0); \
  acc[(mh)*4+(mi)][3] = __builtin_amdgcn_mfma_f32_16x16x32_bf16((A_)[(mi)], (Bv)[3], acc[(mh)*4+(mi)][3], 0, 0, 0); \
} while (0)

#define TILE_BODY(t, BUSE, BLOAD) do { \
  const int _s0 = (2 * (t)) & 7, _s1 = _s0 | 1, _s2 = (2 * (t) + 2) & 7; \
  const bool _last = ((t) == nT - 1); \
  /* ph0: mh0 x ks0 */ \
  BAR(); LGKM(0); PRIO1; \
  MB4(0, 0, afr0, (BUSE)[0]); SB0; RDA(_s0, 1, 0, afr1); SB0; \
  MB4(0, 1, afr0, (BUSE)[0]); SB0; RDA(_s0, 1, 1, afr1); SB0; \
  MB4(0, 2, afr0, (BUSE)[0]); SB0; RDA(_s0, 1, 2, afr1); SB0; \
  MB4(0, 3, afr0, (BUSE)[0]); SB0; RDA(_s0, 1, 3, afr1); PRIO0; \
  /* ph1: mh1 x ks0 | stage A(2t+4); load B(t+1) */ \
  BAR(); stage_half(2 * (t) + 4); SB0; \
  if (!_last) { LOADB8((t) + 1, BLOAD); } SB0; \
  LGKM(0); PRIO1; \
  MB4(1, 0, afr1, (BUSE)[0]); SB0; RDA(_s1, 0, 0, afr0); SB0; \
  MB4(1, 1, afr1, (BUSE)[0]); SB0; RDA(_s1, 0, 1, afr0); SB0; \
  MB4(1, 2, afr1, (BUSE)[0]); SB0; RDA(_s1, 0, 2, afr0); SB0; \
  MB4(1, 3, afr1, (BUSE)[0]); SB0; RDA(_s1, 0, 3, afr0); PRIO0; \
  /* ph2: mh0 x ks1 */ \
  BAR(); LGKM(0); PRIO1; \
  MB4(0, 0, afr0, (BUSE)[1]); SB0; RDA(_s1, 1, 0, afr1); SB0; \
  MB4(0, 1, afr0, (BUSE)[1]); SB0; RDA(_s1, 1, 1, afr1); SB0; \
  MB4(0, 2, afr0, (BUSE)[1]); SB0; RDA(_s1, 1, 2, afr1); SB0; \
  MB4(0, 3, afr0, (BUSE)[1]); SB0; RDA(_s1, 1, 3, afr1); PRIO0; \
  /* ph3: mh1 x ks1 | stage A(2t+5); pre-read A(t+1,ks0,mh0); VMW(2) */ \
  BAR(); stage_half(2 * (t) + 5); SB0; \
  LGKM(0); PRIO1; \
  if (!_last) { \
    MB4(1, 0, afr1, (BUSE)[1]); SB0; RDA(_s2, 0, 0, afr0); SB0; \
    MB4(1, 1, afr1, (BUSE)[1]); SB0; RDA(_s2, 0, 1, afr0); SB0; \
    MB4(1, 2, afr1, (BUSE)[1]); SB0; RDA(_s2, 0, 2, afr0); SB0; \
    MB4(1, 3, afr1, (BUSE)[1]); SB0; RDA(_s2, 0, 3, afr0); \
  } else { \
    MB4(1, 0, afr1, (BUSE)[1]); MB4(1, 1, afr1, (BUSE)[1]); \
    MB4(1, 2, afr1, (BUSE)[1]); MB4(1, 3, afr1, (BUSE)[1]); \
  } \
  PRIO0; \
  VMW(2); \
} while (0)

  // prologue: B(0) FIRST, then A halves 0..3; VMW(2) retires B0,A0,A1,A2
  // and leaves exactly A3 — the loop-entry invariant.
  LOADB8(0, bE);
  SB0;
  stage_half(0); stage_half(1); stage_half(2); stage_half(3);
  VMW(2);
  BAR();
  RDA(0, 0, 0, afr0); RDA(0, 0, 1, afr0); RDA(0, 0, 2, afr0); RDA(0, 0, 3, afr0);

  for (int u = 0; u < nT; u += 2) {
    TILE_BODY(u,     bE, bO);
    TILE_BODY(u + 1, bO, bE);
  }

#undef TILE_BODY
#undef MB4
#undef RDA
#undef LOADB8

  // epilogue — C/D layout: col = lane&15, row = (lane>>4)*4 + j
#pragma unroll
  for (int m = 0; m < 8; ++m)
#pragma unroll
    for (int n = 0; n < 4; ++n)
#pragma unroll
      for (int j = 0; j < 4; ++j) {
        const long row = row0 + wr * 128 + m * 16 + klane * 4 + j;
        const long col = col0 + wc * 64 + n * 16 + rsel;
        out[row * N + col] = acc[m][n][j] + bias[col];
      }
}

// ---------------------------------------------------------------- launch

extern "C" void kernel_launch(void* const* d_in, const int* in_sizes, int n_in,
                              void* d_out, int out_size, void* d_ws, size_t ws_size,
                              hipStream_t stream) {
  (void)in_sizes; (void)n_in; (void)out_size; (void)ws_size;
  const float* x  = (const float*)d_in[0];
  const float* W  = (const float*)d_in[1];
  const float* b  = (const float*)d_in[2];
  const float* A  = (const float*)d_in[3];
  const float* B  = (const float*)d_in[4];
  const float* dw = (const float*)d_in[5];
  const int*   sd = (const int*)d_in[6];
  float* out = (float*)d_out;

  char* ws = (char*)d_ws;
  bf16* xb    = (bf16*)(ws);                          // 64 MB
  bf16* weff  = (bf16*)(ws + ((size_t)64 << 20));     // 32 MB
  bf16* bg    = (bf16*)(ws + ((size_t)96 << 20));     //  2 MB
  bf16* acatT = (bf16*)(ws + ((size_t)98 << 20));     //  2 MB

  cast_x_kernel<<<(T_TOK * DIN / 8) / 256, 256, 0, stream>>>(x, xb);
  build_bg_kernel<<<(DOUT * KLORA) / 256, 256, 0, stream>>>(B, dw, sd, bg);
  transpose_a_kernel<<<dim3(DIN / 32, KLORA / 32), 256, 0, stream>>>(A, acatT);

  // W_eff = bf16(W + Bg @ AcatT^T)   : M=DOUT, N=DIN, K=256
  gemm_bt<<<(DOUT / 128) * (DIN / 128), 256, 0, stream>>>(
      bg, acatT, W, weff, DOUT, DIN, KLORA);

  // out = xb @ W_eff^T + b           : M=T, N=DOUT, K=DIN
  static_assert((T_TOK % 256) == 0 && (DOUT % 256) == 0 && (DIN % 64) == 0, "");
  hipFuncSetAttribute(reinterpret_cast<const void*>(gemm256),
                      hipFuncAttributeMaxDynamicSharedMemorySize, 131072);
  gemm256<<<(T_TOK / 256) * (DOUT / 256), 512, 131072, stream>>>(
      xb, weff, b, out, T_TOK, DOUT, DIN);
}

// Round 12
// 324.493 us; speedup vs baseline: 4.0411x; 4.0411x over previous
//
#include <hip/hip_runtime.h>
#include <hip/hip_bf16.h>

typedef __bf16 bf16;
typedef __attribute__((ext_vector_type(8))) __bf16 bf16x8;
typedef __attribute__((ext_vector_type(4))) float f32x4;

#define T_TOK 8192
#define DIN   4096
#define DOUT  4096
#define RNK   16
#define NS    16
#define KLORA (NS * RNK)   // 256
#define GATE  0.12f

typedef __attribute__((address_space(1))) const void gconst_t;
typedef __attribute__((address_space(3))) void lds_t;

__device__ __forceinline__ void gload_lds16(const void* g, void* l) {
  __builtin_amdgcn_global_load_lds((gconst_t*)g, (lds_t*)l, 16, 0, 0);
}

#define BAR() do { asm volatile("" ::: "memory"); \
                   __builtin_amdgcn_s_barrier();  \
                   asm volatile("" ::: "memory"); } while (0)
#define VMW(n) asm volatile("s_waitcnt vmcnt(" #n ")" ::: "memory")
#define LGKM(n) do { asm volatile("s_waitcnt lgkmcnt(" #n ")" ::: "memory"); \
                     __builtin_amdgcn_sched_barrier(0); } while (0)
#define SB0 __builtin_amdgcn_sched_barrier(0)

// ---------------------------------------------------------------- fused prep (role-split blocks)
// blocks [0, 16384): x (f32) -> xb (bf16), 8 elems/thread
// blocks [16384, 20480): Bg[o][k] = gate(dw[sd[k>>4]]) * B[k>>4][o][k&15]
// blocks [20480, 21504): AcatT[d][k] = bf16(A[k][d])  (A flat [256][DIN]);
//   1024 tiles = 128 d-tiles x 8 k-tiles (r11 bug: had only 512 -> half of
//   acatT stayed poisoned).
__global__ __launch_bounds__(256)
void prep_all_kernel(const float* __restrict__ x, bf16* __restrict__ xb,
                     const float* __restrict__ B, const float* __restrict__ dw,
                     const int* __restrict__ sd, bf16* __restrict__ bg,
                     const float* __restrict__ A, bf16* __restrict__ at) {
  __shared__ float tl[32][33];
  const int bid = blockIdx.x;
  if (bid < 16384) {
    const long i = ((long)bid * 256 + threadIdx.x) * 8;
    const float4 v0 = *(const float4*)(x + i);
    const float4 v1 = *(const float4*)(x + i + 4);
    bf16x8 o;
    o[0] = (bf16)v0.x; o[1] = (bf16)v0.y; o[2] = (bf16)v0.z; o[3] = (bf16)v0.w;
    o[4] = (bf16)v1.x; o[5] = (bf16)v1.y; o[6] = (bf16)v1.z; o[7] = (bf16)v1.w;
    *(bf16x8*)(xb + i) = o;
  } else if (bid < 16384 + 4096) {
    const int t = (bid - 16384) * 256 + threadIdx.x;
    const int o = t >> 8, k = t & 255, s = k >> 4, r = k & 15;
    const float w = dw[sd[s]];
    const float g = (w > GATE) ? w : 0.f;
    bg[t] = (bf16)(g * B[((size_t)s * DOUT + o) * RNK + r]);
  } else {
    const int tb = bid - 16384 - 4096;       // 1024 tiles: 128 d-tiles x 8 k-tiles
    const int d0 = (tb & 127) * 32, k0 = (tb >> 7) * 32;
    const int tx = threadIdx.x & 31, ty = threadIdx.x >> 5;
#pragma unroll
    for (int i = 0; i < 32; i += 8)
      tl[ty + i][tx] = A[(size_t)(k0 + ty + i) * DIN + d0 + tx];
    __syncthreads();
#pragma unroll
    for (int i = 0; i < 32; i += 8)
      at[(size_t)(d0 + ty + i) * KLORA + k0 + tx] = (bf16)tl[tx][ty + i];
  }
}

// ---------------------------------------------------------------- 128^2 GEMM (W_eff only)
__global__ __launch_bounds__(256)
void gemm_bt(const bf16* __restrict__ Am, const bf16* __restrict__ Bm,
             const float* __restrict__ extra, bf16* __restrict__ outB,
             int M, int N, int K) {
  constexpr int BM = 128, BN = 128, BK = 32;
  __shared__ __align__(16) bf16 At[BM * BK];
  __shared__ __align__(16) bf16 Bt[BN * BK];

  const int tid  = threadIdx.x;
  const int wave = tid >> 6, lane = tid & 63;

  const int nwg = gridDim.x, bid = blockIdx.x;
  const int qq  = nwg >> 3;
  const int sw  = (bid & 7) * qq + (bid >> 3);
  const int ntN = N / BN;
  const long row0 = (long)(sw / ntN) * BM;
  const long col0 = (long)(sw % ntN) * BN;

  f32x4 acc[4][4] = {};
  const int kSteps = K / BK;

  auto stage = [&](int ks) {
    const long k0 = (long)ks * BK;
#pragma unroll
    for (int r = 0; r < 2; ++r) {
      const int off = tid * 16 + r * 4096;
      const int row = off >> 6;
      const int el  = (off & 63) >> 1;
      char* ldsA = (char*)At + (wave << 10) + (r << 12);
      char* ldsB = (char*)Bt + (wave << 10) + (r << 12);
      gload_lds16(Am + (row0 + row) * K + k0 + el, ldsA);
      gload_lds16(Bm + (col0 + row) * K + k0 + el, ldsB);
    }
  };

  stage(0);
  for (int ks = 0; ks < kSteps; ++ks) {
    __syncthreads();
    bf16x8 afr[4], bfr[4];
    const int koff = (lane >> 4) << 3;
    const int rsel = lane & 15;
    const int wr = wave >> 1, wc = wave & 1;
#pragma unroll
    for (int m = 0; m < 4; ++m)
      afr[m] = *(const bf16x8*)&At[((wr << 6) + (m << 4) + rsel) * BK + koff];
#pragma unroll
    for (int n = 0; n < 4; ++n)
      bfr[n] = *(const bf16x8*)&Bt[((wc << 6) + (n << 4) + rsel) * BK + koff];
    __syncthreads();
    if (ks + 1 < kSteps) stage(ks + 1);
#pragma unroll
    for (int m = 0; m < 4; ++m)
#pragma unroll
      for (int n = 0; n < 4; ++n)
        acc[m][n] = __builtin_amdgcn_mfma_f32_16x16x32_bf16(afr[m], bfr[n],
                                                            acc[m][n], 0, 0, 0);
  }

  const int wr = wave >> 1, wc = wave & 1;
#pragma unroll
  for (int m = 0; m < 4; ++m)
#pragma unroll
    for (int n = 0; n < 4; ++n)
#pragma unroll
      for (int j = 0; j < 4; ++j) {
        const long row = row0 + wr * 64 + m * 16 + ((lane >> 4) << 2) + j;
        const long col = col0 + wc * 64 + n * 16 + (lane & 15);
        outB[row * N + col] = (bf16)(acc[m][n][j] + extra[row * N + col]);
      }
}

// ---------------------------------------------------------------- 256^2 GEMM (r7 structure, best measured: 255us)
// out[row][col] = sum_k Am[row][k]*Bm[col][k] + bias[col]   (f32 out)
// BM=BN=256, BK=64 (2 ksubs of 32). 8 waves (2M x 4N), 512 threads.
// Halves of tile t: A0=4t+0,B0=4t+1,A1=4t+2,B1=4t+3; slot = H&7 (16KB each).
// Stage cadence ph0..ph3: 4t+{5,6,7,8}. VMW(4) at end of ph0 (retires A1,B1
// of t) and end of ph2 (retires A0,B0 of t+1), each globalized by next BAR.
// ds_reads for phase P+1 interleaved INSIDE phase P's MFMA cluster.
__global__ __launch_bounds__(512, 2)
void gemm256(const bf16* __restrict__ Am, const bf16* __restrict__ Bm,
             const float* __restrict__ bias, float* __restrict__ out,
             int M, int N, int K) {
  extern __shared__ char smem[];
  const int tid  = threadIdx.x;
  const int wave = tid >> 6, lane = tid & 63;
  const int wr = wave >> 2, wc = wave & 3;       // 2 x 4 wave grid
  const int rsel = lane & 15, klane = lane >> 4;

  const int nwg = gridDim.x, bid = blockIdx.x;   // nwg multiple of 8
  const int sw  = (bid & 7) * (nwg >> 3) + (bid >> 3);
  const int ntN = N >> 8;
  const long row0 = (long)(sw / ntN) << 8;
  const long col0 = (long)(sw % ntN) << 8;

  // staging: dest (linear) = slot<<14 + (wave*2+r)<<10 + lane*16
  long srcA[2], srcB[2];
  int  ldsd[2];
  {
    const int rlo = lane >> 2;
    const int kbe = (((lane & 3) * 16) ^ (((lane >> 5) & 1) << 5)) >> 1;
#pragma unroll
    for (int r = 0; r < 2; ++r) {
      const int row = wave * 32 + r * 16 + rlo;
      srcA[r] = (row0 + row) * (long)K + kbe;
      srcB[r] = (col0 + row) * (long)K + kbe;
      ldsd[r] = (wave * 2 + r) << 10;
    }
  }

  const int nT = K >> 6;

  auto stage_half = [&](int H) {
    if (H >= 4 * nT) return;
    const int  slot = H & 7;
    const long kofs = (long)(H >> 2) * 64 + (long)((H >> 1) & 1) * 32;
    if (H & 1) {
#pragma unroll
      for (int r = 0; r < 2; ++r)
        gload_lds16(Bm + srcB[r] + kofs, smem + (slot << 14) + ldsd[r]);
    } else {
#pragma unroll
      for (int r = 0; r < 2; ++r)
        gload_lds16(Am + srcA[r] + kofs, smem + (slot << 14) + ldsd[r]);
    }
  };

  // read side: byte = row*64 + (klane*16 ^ ((row&8)<<2)); row&8 == rsel&8
  const int laneoff = rsel * 64 + ((klane * 16) ^ ((rsel & 8) << 2));

  f32x4 acc[8][4] = {};
  bf16x8 afr0[4], afr1[4], bfr0[4], bfr1[4];

#define RDA(slot, mh, mi, dst) \
  (dst)[(mi)] = *(const bf16x8*)(smem + ((slot) << 14) + \
                 (((wr << 7) + (mh) * 64 + (mi) * 16) << 6) + laneoff)
#define RDB(slot, n, dst) \
  (dst)[(n)] = *(const bf16x8*)(smem + ((slot) << 14) + \
                (((wc << 6) + (n) * 16) << 6) + laneoff)
#define MB(mh, mi, A_, B_) do { \
  acc[(mh)*4+(mi)][0] = __builtin_amdgcn_mfma_f32_16x16x32_bf16((A_)[(mi)], (B_)[0], acc[(mh)*4+(mi)][0], 0, 0, 0); \
  acc[(mh)*4+(mi)][1] = __builtin_amdgcn_mfma_f32_16x16x32_bf16((A_)[(mi)], (B_)[1], acc[(mh)*4+(mi)][1], 0, 0, 0); \
  acc[(mh)*4+(mi)][2] = __builtin_amdgcn_mfma_f32_16x16x32_bf16((A_)[(mi)], (B_)[2], acc[(mh)*4+(mi)][2], 0, 0, 0); \
  acc[(mh)*4+(mi)][3] = __builtin_amdgcn_mfma_f32_16x16x32_bf16((A_)[(mi)], (B_)[3], acc[(mh)*4+(mi)][3], 0, 0, 0); \
} while (0)

  // prologue: stage halves 0..4; VMW(6) -> halves 0,1 landed (mine);
  // BAR globalizes; issue ph0's operand reads.
  stage_half(0); stage_half(1); stage_half(2); stage_half(3); stage_half(4);
  VMW(6);
  BAR();
  RDB(1, 0, bfr0); RDB(1, 1, bfr0); RDB(1, 2, bfr0); RDB(1, 3, bfr0);
  RDA(0, 0, 0, afr0); RDA(0, 0, 1, afr0); RDA(0, 0, 2, afr0); RDA(0, 0, 3, afr0);

  for (int t = 0; t < nT; ++t) {
    const int b  = (t & 1) << 2;
    const int b2 = b ^ 4;
    const bool last = (t == nT - 1);
    // ---- ph0: mh0 x ksub0 (afr0,bfr0); pre-read afr1 <- A[mh1] slot b|0
    BAR();
    stage_half(4 * t + 5);
    LGKM(0);
    __builtin_amdgcn_s_setprio(1);
    MB(0, 0, afr0, bfr0); SB0; RDA(b | 0, 1, 0, afr1); SB0;
    MB(0, 1, afr0, bfr0); SB0; RDA(b | 0, 1, 1, afr1); SB0;
    MB(0, 2, afr0, bfr0); SB0; RDA(b | 0, 1, 2, afr1); SB0;
    MB(0, 3, afr0, bfr0); SB0; RDA(b | 0, 1, 3, afr1);
    __builtin_amdgcn_s_setprio(0);
    if (last) { VMW(0); } else { VMW(4); }       // retires A1(t),B1(t)
    // ---- ph1: mh1 x ksub0 (afr1,bfr0); pre-read bfr1 (b|3), afr0 (b|2,mh0)
    BAR();
    stage_half(4 * t + 6);
    LGKM(0);
    __builtin_amdgcn_s_setprio(1);
    MB(1, 0, afr1, bfr0); SB0; RDB(b | 3, 0, bfr1); RDB(b | 3, 1, bfr1); SB0;
    MB(1, 1, afr1, bfr0); SB0; RDB(b | 3, 2, bfr1); RDB(b | 3, 3, bfr1); SB0;
    MB(1, 2, afr1, bfr0); SB0; RDA(b | 2, 0, 0, afr0); RDA(b | 2, 0, 1, afr0); SB0;
    MB(1, 3, afr1, bfr0); SB0; RDA(b | 2, 0, 2, afr0); RDA(b | 2, 0, 3, afr0);
    __builtin_amdgcn_s_setprio(0);
    // ---- ph2: mh0 x ksub1 (afr0,bfr1); pre-read afr1 (b|2,mh1)
    BAR();
    stage_half(4 * t + 7);
    LGKM(0);
    __builtin_amdgcn_s_setprio(1);
    MB(0, 0, afr0, bfr1); SB0; RDA(b | 2, 1, 0, afr1); SB0;
    MB(0, 1, afr0, bfr1); SB0; RDA(b | 2, 1, 1, afr1); SB0;
    MB(0, 2, afr0, bfr1); SB0; RDA(b | 2, 1, 2, afr1); SB0;
    MB(0, 3, afr0, bfr1); SB0; RDA(b | 2, 1, 3, afr1);
    __builtin_amdgcn_s_setprio(0);
    VMW(4);                                      // retires A0(t+1),B0(t+1)
    // ---- ph3: mh1 x ksub1 (afr1,bfr1); pre-read next tile's bfr0,afr0
    BAR();
    stage_half(4 * t + 8);
    LGKM(0);
    __builtin_amdgcn_s_setprio(1);
    if (!last) {
      MB(1, 0, afr1, bfr1); SB0; RDB(b2 | 1, 0, bfr0); RDB(b2 | 1, 1, bfr0); SB0;
      MB(1, 1, afr1, bfr1); SB0; RDB(b2 | 1, 2, bfr0); RDB(b2 | 1, 3, bfr0); SB0;
      MB(1, 2, afr1, bfr1); SB0; RDA(b2 | 0, 0, 0, afr0); RDA(b2 | 0, 0, 1, afr0); SB0;
      MB(1, 3, afr1, bfr1); SB0; RDA(b2 | 0, 0, 2, afr0); RDA(b2 | 0, 0, 3, afr0);
    } else {
      MB(1, 0, afr1, bfr1); MB(1, 1, afr1, bfr1);
      MB(1, 2, afr1, bfr1); MB(1, 3, afr1, bfr1);
    }
    __builtin_amdgcn_s_setprio(0);
  }

#undef RDA
#undef RDB
#undef MB

  // epilogue — C/D layout: col = lane&15, row = (lane>>4)*4 + j
#pragma unroll
  for (int m = 0; m < 8; ++m)
#pragma unroll
    for (int n = 0; n < 4; ++n)
#pragma unroll
      for (int j = 0; j < 4; ++j) {
        const long row = row0 + wr * 128 + m * 16 + klane * 4 + j;
        const long col = col0 + wc * 64 + n * 16 + rsel;
        out[row * N + col] = acc[m][n][j] + bias[col];
      }
}

// ---------------------------------------------------------------- launch

extern "C" void kernel_launch(void* const* d_in, const int* in_sizes, int n_in,
                              void* d_out, int out_size, void* d_ws, size_t ws_size,
                              hipStream_t stream) {
  (void)in_sizes; (void)n_in; (void)out_size; (void)ws_size;
  const float* x  = (const float*)d_in[0];
  const float* W  = (const float*)d_in[1];
  const float* b  = (const float*)d_in[2];
  const float* A  = (const float*)d_in[3];
  const float* B  = (const float*)d_in[4];
  const float* dw = (const float*)d_in[5];
  const int*   sd = (const int*)d_in[6];
  float* out = (float*)d_out;

  char* ws = (char*)d_ws;
  bf16* xb    = (bf16*)(ws);                          // 64 MB
  bf16* weff  = (bf16*)(ws + ((size_t)64 << 20));     // 32 MB
  bf16* bg    = (bf16*)(ws + ((size_t)96 << 20));     //  2 MB
  bf16* acatT = (bf16*)(ws + ((size_t)98 << 20));     //  2 MB

  // 1) fused memory-bound prep: x-cast | Bg | A^T (1024 transpose tiles!)
  prep_all_kernel<<<16384 + 4096 + 1024, 256, 0, stream>>>(
      x, xb, B, dw, sd, bg, A, acatT);

  // 2) W_eff = bf16(W + Bg @ AcatT^T)   : M=DOUT, N=DIN, K=256
  gemm_bt<<<(DOUT / 128) * (DIN / 128), 256, 0, stream>>>(
      bg, acatT, W, weff, DOUT, DIN, KLORA);

  // 3) out = xb @ W_eff^T + b           : M=T, N=DOUT, K=DIN
  static_assert((T_TOK % 256) == 0 && (DOUT % 256) == 0 && (DIN % 64) == 0, "");
  hipFuncSetAttribute(reinterpret_cast<const void*>(gemm256),
                      hipFuncAttributeMaxDynamicSharedMemorySize, 131072);
  gemm256<<<(T_TOK / 256) * (DOUT / 256), 512, 131072, stream>>>(
      xb, weff, b, out, T_TOK, DOUT, DIN);
}